// Round 1
// baseline (92.321 us; speedup 1.0000x reference)
//
#include <hip/hip_runtime.h>
#include <math.h>

#define NGRAPH 128
#define NNODE  200
#define FIN    200
#define DIM    32
#define EPER   6400
#define ETOT   819200
#define KP1    100
#define KP2    50

// sW layout offsets (floats)
#define W1B_OFF  0
#define W2A_OFF  1024
#define W2B_OFF  2048
#define B1A_OFF  3072
#define B1B_OFF  3104
#define B2A_OFF  3136
#define B2B_OFF  3168
#define PW1_OFF  3200
#define PW2_OFF  3232
#define NRM1_OFF 3264
#define NRM2_OFF 3265
#define SW_SIZE  3280

// Tiled [ROWS]x32 @ 32x32 matmul from LDS. Threads 0..ROWS-1 active, each
// computes a 4x8 output tile. ROWS must be a multiple of 4.
template <int ROWS, bool RELU, bool BIAS>
__device__ inline void mm_k32(const float* __restrict__ A,
                              const float* __restrict__ W,
                              float* __restrict__ O,
                              const float* __restrict__ bias,
                              int tid) {
  if (tid < ROWS) {
    const int rg = tid >> 2, cg = tid & 3;
    const int n0 = rg * 4, d0 = cg * 8;
    float acc[4][8];
#pragma unroll
    for (int r = 0; r < 4; ++r)
#pragma unroll
      for (int c = 0; c < 8; ++c) acc[r][c] = 0.f;
#pragma unroll 8
    for (int k = 0; k < 32; ++k) {
      const float4 wa = *(const float4*)&W[k * 32 + d0];
      const float4 wb = *(const float4*)&W[k * 32 + d0 + 4];
#pragma unroll
      for (int r = 0; r < 4; ++r) {
        const float xs = A[(n0 + r) * 32 + k];
        acc[r][0] += xs * wa.x; acc[r][1] += xs * wa.y;
        acc[r][2] += xs * wa.z; acc[r][3] += xs * wa.w;
        acc[r][4] += xs * wb.x; acc[r][5] += xs * wb.y;
        acc[r][6] += xs * wb.z; acc[r][7] += xs * wb.w;
      }
    }
#pragma unroll
    for (int r = 0; r < 4; ++r)
#pragma unroll
      for (int c = 0; c < 8; ++c) {
        float v = acc[r][c];
        if (BIAS) v += bias[d0 + c];
        if (RELU) v = fmaxf(v, 0.f);
        O[(n0 + r) * 32 + d0 + c] = v;
      }
  }
}

__global__ __launch_bounds__(256, 1) void gin_fused(
    const float* __restrict__ x, const int* __restrict__ ei,
    const float* __restrict__ w1a, const float* __restrict__ b1a,
    const float* __restrict__ w1b, const float* __restrict__ b1b,
    const float* __restrict__ w2a, const float* __restrict__ b2a,
    const float* __restrict__ w2b, const float* __restrict__ b2b,
    const float* __restrict__ pw1, const float* __restrict__ pw2,
    const float* __restrict__ fc1w, const float* __restrict__ fc1b,
    const float* __restrict__ fc2w, const float* __restrict__ fc2b,
    const float* __restrict__ fc3w, const float* __restrict__ fc3b,
    const float* __restrict__ bn1g, const float* __restrict__ bn1b,
    const float* __restrict__ bn1m, const float* __restrict__ bn1v,
    const float* __restrict__ bn2g, const float* __restrict__ bn2b,
    const float* __restrict__ bn2m, const float* __restrict__ bn2v,
    float* __restrict__ out) {
  __shared__ __align__(16) float sA[6400];   // w1a, then CSR src lists (as int)
  __shared__ __align__(16) float sB[6400];   // y1, then y2
  __shared__ __align__(16) float sC[6400];   // aggr1/t1, then aggr2/t2
  __shared__ __align__(16) float sD[6400];   // h (conv1 out), then hc2
  __shared__ __align__(16) float sG[3200];   // hp1, then hp2
  __shared__ __align__(16) float sW[SW_SIZE];
  __shared__ unsigned short sEdge[6400];     // packed (src<<8)|dst, local ids
  __shared__ int sCnt[256];
  __shared__ int sStart[256];
  __shared__ int sOfs[256];
  __shared__ float sScore[256];
  __shared__ int sNewid[256];
  __shared__ float sZ[64];
  __shared__ float sZ1[128];
  __shared__ float sZ2[256];
  __shared__ float sLg[2];

  const int tid = threadIdx.x;
  const int g = blockIdx.x;
  int* const srclist = (int*)sA;

  // ================= stage 0: stage weights in LDS =================
  for (int i = tid; i < 6400; i += 256) sA[i] = w1a[i];
  for (int i = tid; i < 1024; i += 256) {
    sW[W1B_OFF + i] = w1b[i];
    sW[W2A_OFF + i] = w2a[i];
    sW[W2B_OFF + i] = w2b[i];
  }
  if (tid < 32) {
    sW[B1A_OFF + tid] = b1a[tid];
    sW[B1B_OFF + tid] = b1b[tid];
    sW[B2A_OFF + tid] = b2a[tid];
    sW[B2B_OFF + tid] = b2b[tid];
    sW[PW1_OFF + tid] = pw1[tid];
    sW[PW2_OFF + tid] = pw2[tid];
  }
  __syncthreads();
  if (tid == 0) {
    float s = 0.f;
    for (int k = 0; k < 32; ++k) s += sW[PW1_OFF + k] * sW[PW1_OFF + k];
    sW[NRM1_OFF] = sqrtf(s);
  } else if (tid == 64) {
    float s = 0.f;
    for (int k = 0; k < 32; ++k) s += sW[PW2_OFF + k] * sW[PW2_OFF + k];
    sW[NRM2_OFF] = sqrtf(s);
  }
  __syncthreads();

  // ================= stage B: y1 = x @ w1a  (200x200 @ 200x32) ============
  // Linearity: (x + aggr_x) @ W = xW + aggr(xW). Project first, aggregate after.
  if (tid < 200) {
    const int rg = tid >> 2, cg = tid & 3;
    const int n0 = rg * 4, d0 = cg * 8;
    float acc[4][8];
#pragma unroll
    for (int r = 0; r < 4; ++r)
#pragma unroll
      for (int c = 0; c < 8; ++c) acc[r][c] = 0.f;
    const float* xg = x + (size_t)g * NNODE * FIN;
    for (int k = 0; k < FIN; k += 4) {
      float4 xv[4];
#pragma unroll
      for (int r = 0; r < 4; ++r)
        xv[r] = *(const float4*)&xg[(n0 + r) * FIN + k];
#pragma unroll
      for (int j = 0; j < 4; ++j) {
        const float4 wa = *(const float4*)&sA[(k + j) * 32 + d0];
        const float4 wb = *(const float4*)&sA[(k + j) * 32 + d0 + 4];
#pragma unroll
        for (int r = 0; r < 4; ++r) {
          const float xs = (j == 0) ? xv[r].x : (j == 1) ? xv[r].y
                                   : (j == 2) ? xv[r].z : xv[r].w;
          acc[r][0] += xs * wa.x; acc[r][1] += xs * wa.y;
          acc[r][2] += xs * wa.z; acc[r][3] += xs * wa.w;
          acc[r][4] += xs * wb.x; acc[r][5] += xs * wb.y;
          acc[r][6] += xs * wb.z; acc[r][7] += xs * wb.w;
        }
      }
    }
#pragma unroll
    for (int r = 0; r < 4; ++r)
#pragma unroll
      for (int c = 0; c < 8; ++c) sB[(n0 + r) * 32 + d0 + c] = acc[r][c];
  }
  __syncthreads();

  // ================= sort1: counting sort edges by dst =================
  sCnt[tid] = 0;
  sOfs[tid] = 0;
  __syncthreads();
  {
    const int eb = g * EPER, nb = g * NNODE;
    for (int e = tid; e < EPER; e += 256) {
      const int s = ei[eb + e] - nb;
      const int d = ei[ETOT + eb + e] - nb;
      sEdge[e] = (unsigned short)((s << 8) | d);
      atomicAdd(&sCnt[d], 1);
    }
  }
  __syncthreads();
  {  // exclusive prefix sum of sCnt -> sStart (Hillis-Steele over 256)
    const int myc = sCnt[tid];
    sStart[tid] = myc;
    __syncthreads();
    for (int off = 1; off < 256; off <<= 1) {
      const int t = (tid >= off) ? sStart[tid - off] : 0;
      __syncthreads();
      sStart[tid] += t;
      __syncthreads();
    }
    const int ex = sStart[tid] - myc;
    __syncthreads();
    sStart[tid] = ex;
  }
  __syncthreads();
  for (int e = tid; e < EPER; e += 256) {  // scatter src ids grouped by dst
    const unsigned short p = sEdge[e];
    const int s = p >> 8, d = p & 255;
    const int pos = sStart[d] + atomicAdd(&sOfs[d], 1);
    srclist[pos] = s;
  }
  __syncthreads();

  // ================= aggr1: aggr[n] = sum y1[src] over in-edges ============
  {
    const int slot = tid >> 3;        // node slot 0..31
    const int dp = (tid & 7) * 4;     // float4 part
    for (int it = 0; it < 7; ++it) {
      const int n = it * 32 + slot;
      if (n < NNODE) {
        float ax = 0.f, ay = 0.f, az = 0.f, aw = 0.f;
        const int jb = sStart[n], je = jb + sCnt[n];
        for (int j = jb; j < je; ++j) {
          const int s = srclist[j];
          const float4 v = *(const float4*)&sB[s * 32 + dp];
          ax += v.x; ay += v.y; az += v.z; aw += v.w;
        }
        float4 o; o.x = ax; o.y = ay; o.z = az; o.w = aw;
        *(float4*)&sC[n * 32 + dp] = o;
      }
    }
  }
  __syncthreads();

  // t1 = relu(y1 + aggr1 + b1a)  (in place in sC)
  for (int i = tid; i < 6400; i += 256)
    sC[i] = fmaxf(sB[i] + sC[i] + sW[B1A_OFF + (i & 31)], 0.f);
  __syncthreads();

  // h = relu(t1 @ w1b + b1b)  -> sD   (conv1 output incl. outer relu)
  mm_k32<200, true, true>(sC, &sW[W1B_OFF], sD, &sW[B1B_OFF], tid);
  __syncthreads();

  // ================= pool1: top-100 of 200 =================
  if (tid < 200) {
    float dot = 0.f;
    for (int k = 0; k < 32; ++k) dot += sD[tid * 32 + k] * sW[PW1_OFF + k];
    sScore[tid] = tanhf(dot / sW[NRM1_OFF]);
  }
  __syncthreads();
  if (tid < 200) {  // stable descending rank == lax.top_k order
    const float s = sScore[tid];
    int r = 0;
    for (int m = 0; m < 200; ++m) {
      const float sm = sScore[m];
      r += (sm > s) || (sm == s && m < tid);
    }
    sNewid[tid] = (r < KP1) ? r : -1;
    if (r < KP1) out[2 * NGRAPH + g * KP1 + r] = 1.f / (1.f + expf(-s));
  }
  __syncthreads();
  if (tid < 200) {  // hp1[rank] = h[n] * score[n]
    const int r = sNewid[tid];
    if (r >= 0) {
      const float sc = sScore[tid];
      for (int d4 = 0; d4 < 32; d4 += 4) {
        float4 v = *(const float4*)&sD[tid * 32 + d4];
        v.x *= sc; v.y *= sc; v.z *= sc; v.w *= sc;
        *(float4*)&sG[r * 32 + d4] = v;
      }
    }
  }
  __syncthreads();
  // x1 readout: gmp || gap over hp1
  if (tid < 32) {
    float mx = -INFINITY, sm = 0.f;
    for (int r = 0; r < KP1; ++r) {
      const float v = sG[r * 32 + tid];
      mx = fmaxf(mx, v); sm += v;
    }
    sZ[tid] = mx;
    sZ[32 + tid] = sm / (float)KP1;
  }
  __syncthreads();

  // ================= conv2 =================
  // y2 = hp1 @ w2a  -> sB (rows 0..99)
  mm_k32<100, false, false>(sG, &sW[W2A_OFF], sB, nullptr, tid);
  __syncthreads();

  // sort2: counting sort of surviving remapped edges
  sCnt[tid] = 0;
  sOfs[tid] = 0;
  __syncthreads();
  for (int e = tid; e < EPER; e += 256) {
    const unsigned short p = sEdge[e];
    const int s1 = sNewid[p >> 8], d1 = sNewid[p & 255];
    if (s1 >= 0 && d1 >= 0) atomicAdd(&sCnt[d1], 1);
  }
  __syncthreads();
  {
    const int myc = sCnt[tid];
    sStart[tid] = myc;
    __syncthreads();
    for (int off = 1; off < 256; off <<= 1) {
      const int t = (tid >= off) ? sStart[tid - off] : 0;
      __syncthreads();
      sStart[tid] += t;
      __syncthreads();
    }
    const int ex = sStart[tid] - myc;
    __syncthreads();
    sStart[tid] = ex;
  }
  __syncthreads();
  for (int e = tid; e < EPER; e += 256) {
    const unsigned short p = sEdge[e];
    const int s1 = sNewid[p >> 8], d1 = sNewid[p & 255];
    if (s1 >= 0 && d1 >= 0) {
      const int pos = sStart[d1] + atomicAdd(&sOfs[d1], 1);
      srclist[pos] = s1;
    }
  }
  __syncthreads();

  // aggr2 -> sC (rows 0..99)
  {
    const int slot = tid >> 3;
    const int dp = (tid & 7) * 4;
    for (int it = 0; it < 4; ++it) {
      const int n = it * 32 + slot;
      if (n < KP1) {
        float ax = 0.f, ay = 0.f, az = 0.f, aw = 0.f;
        const int jb = sStart[n], je = jb + sCnt[n];
        for (int j = jb; j < je; ++j) {
          const int s = srclist[j];
          const float4 v = *(const float4*)&sB[s * 32 + dp];
          ax += v.x; ay += v.y; az += v.z; aw += v.w;
        }
        float4 o; o.x = ax; o.y = ay; o.z = az; o.w = aw;
        *(float4*)&sC[n * 32 + dp] = o;
      }
    }
  }
  __syncthreads();

  // t2 = relu(y2 + aggr2 + b2a)
  for (int i = tid; i < 3200; i += 256)
    sC[i] = fmaxf(sB[i] + sC[i] + sW[B2A_OFF + (i & 31)], 0.f);
  __syncthreads();

  // hc2 = relu(t2 @ w2b + b2b) -> sD (rows 0..99)
  mm_k32<100, true, true>(sC, &sW[W2B_OFF], sD, &sW[B2B_OFF], tid);
  __syncthreads();

  // ================= pool2: top-50 of 100 =================
  if (tid < 100) {
    float dot = 0.f;
    for (int k = 0; k < 32; ++k) dot += sD[tid * 32 + k] * sW[PW2_OFF + k];
    sScore[tid] = tanhf(dot / sW[NRM2_OFF]);
  }
  __syncthreads();
  if (tid < 100) {
    const float s = sScore[tid];
    int r = 0;
    for (int m = 0; m < 100; ++m) {
      const float sm = sScore[m];
      r += (sm > s) || (sm == s && m < tid);
    }
    sNewid[tid] = (r < KP2) ? r : -1;
    if (r < KP2)
      out[2 * NGRAPH + NGRAPH * KP1 + g * KP2 + r] = 1.f / (1.f + expf(-s));
  }
  __syncthreads();
  if (tid < 100) {  // hp2[rank] = hc2[n] * score[n]
    const int r = sNewid[tid];
    if (r >= 0) {
      const float sc = sScore[tid];
      for (int d4 = 0; d4 < 32; d4 += 4) {
        float4 v = *(const float4*)&sD[tid * 32 + d4];
        v.x *= sc; v.y *= sc; v.z *= sc; v.w *= sc;
        *(float4*)&sG[r * 32 + d4] = v;
      }
    }
  }
  __syncthreads();
  // x2 readout, z = x1 + x2
  if (tid < 32) {
    float mx = -INFINITY, sm = 0.f;
    for (int r = 0; r < KP2; ++r) {
      const float v = sG[r * 32 + tid];
      mx = fmaxf(mx, v); sm += v;
    }
    sZ[tid] += mx;
    sZ[32 + tid] += sm / (float)KP2;
  }
  __syncthreads();

  // ================= MLP head =================
  if (tid < 128) {
    float a = fc1b[tid];
    for (int k = 0; k < 64; ++k) a += sZ[k] * fc1w[k * 128 + tid];
    a = fmaxf(a, 0.f);
    a = (a - bn1m[tid]) * rsqrtf(bn1v[tid] + 1e-5f) * bn1g[tid] + bn1b[tid];
    sZ1[tid] = a;
  }
  __syncthreads();
  {
    float a = fc2b[tid];
    for (int k = 0; k < 128; ++k) a += sZ1[k] * fc2w[k * 256 + tid];
    a = fmaxf(a, 0.f);
    a = (a - bn2m[tid]) * rsqrtf(bn2v[tid] + 1e-5f) * bn2g[tid] + bn2b[tid];
    sZ2[tid] = a;
  }
  __syncthreads();
  if (tid < 2) {
    float a = fc3b[tid];
    for (int k = 0; k < 256; ++k) a += sZ2[k] * fc3w[k * 2 + tid];
    sLg[tid] = a;
  }
  __syncthreads();
  if (tid == 0) {
    const float l0 = sLg[0], l1 = sLg[1];
    const float m = fmaxf(l0, l1);
    const float lse = m + logf(expf(l0 - m) + expf(l1 - m));
    out[g * 2 + 0] = l0 - lse;
    out[g * 2 + 1] = l1 - lse;
  }
}

extern "C" void kernel_launch(void* const* d_in, const int* in_sizes, int n_in,
                              void* d_out, int out_size, void* d_ws,
                              size_t ws_size, hipStream_t stream) {
  (void)in_sizes; (void)n_in; (void)out_size; (void)d_ws; (void)ws_size;
  gin_fused<<<NGRAPH, 256, 0, stream>>>(
      (const float*)d_in[0], (const int*)d_in[1],
      (const float*)d_in[3], (const float*)d_in[4],
      (const float*)d_in[5], (const float*)d_in[6],
      (const float*)d_in[7], (const float*)d_in[8],
      (const float*)d_in[9], (const float*)d_in[10],
      (const float*)d_in[11], (const float*)d_in[12],
      (const float*)d_in[13], (const float*)d_in[14],
      (const float*)d_in[15], (const float*)d_in[16],
      (const float*)d_in[17], (const float*)d_in[18],
      (const float*)d_in[19], (const float*)d_in[20],
      (const float*)d_in[21], (const float*)d_in[22],
      (const float*)d_in[23], (const float*)d_in[24],
      (const float*)d_in[25], (const float*)d_in[26],
      (float*)d_out);
}

// Round 2
// 63.255 us; speedup vs baseline: 1.4595x; 1.4595x over previous
//
#include <hip/hip_runtime.h>
#include <math.h>

#define NGRAPH 128
#define NNODE  200
#define FIN    200
#define DIM    32
#define EPER   6400
#define ETOT   819200
#define KP1    100
#define KP2    50

// sW layout offsets (floats)
#define W1B_OFF  0
#define W2A_OFF  1024
#define W2B_OFF  2048
#define B1A_OFF  3072
#define B1B_OFF  3104
#define B2A_OFF  3136
#define B2B_OFF  3168
#define PW1_OFF  3200
#define PW2_OFF  3232
#define NRM1_OFF 3264
#define NRM2_OFF 3265
#define SW_SIZE  3280

// XOR chunk swizzle for [row][32]-float LDS tiles: physical float index of
// logical (row, chunk) float4. Spreads same-chunk reads of rows rg*4+r across
// 8 bank-groups (fixes 16-way mm conflicts and 32-way column reads).
__device__ __forceinline__ int swz(int row, int chunk) {
  return (row << 5) + (((chunk ^ ((row >> 2) & 7))) << 2);
}

// ============ K1: y = x @ w1a for all graphs (dense 25600x200 @ 200x32) ====
__global__ __launch_bounds__(256, 1) void proj_k(const float* __restrict__ x,
                                                 const float* __restrict__ w1a,
                                                 float* __restrict__ y) {
  __shared__ __align__(16) float sw[FIN * DIM];  // 25.6 KB
  const int tid = threadIdx.x;
  for (int i = tid; i < FIN * DIM; i += 256) sw[i] = w1a[i];
  __syncthreads();
  if (tid >= 200) return;
  const int rg = tid >> 2, cg = tid & 3;
  const int d0 = cg * 8;
  const int r0 = blockIdx.x * 100 + rg * 2;  // 256 blocks x 100 rows = 25600
  const float* x0 = x + (size_t)r0 * FIN;
  float a0[8] = {0, 0, 0, 0, 0, 0, 0, 0};
  float a1[8] = {0, 0, 0, 0, 0, 0, 0, 0};
  for (int k = 0; k < FIN; k += 4) {
    const float4 xa = *(const float4*)&x0[k];
    const float4 xb = *(const float4*)&x0[FIN + k];
#pragma unroll
    for (int j = 0; j < 4; ++j) {
      const float4 wa = *(const float4*)&sw[(k + j) * DIM + d0];
      const float4 wb = *(const float4*)&sw[(k + j) * DIM + d0 + 4];
      const float s0 = (j == 0) ? xa.x : (j == 1) ? xa.y : (j == 2) ? xa.z : xa.w;
      const float s1 = (j == 0) ? xb.x : (j == 1) ? xb.y : (j == 2) ? xb.z : xb.w;
      a0[0] += s0 * wa.x; a0[1] += s0 * wa.y; a0[2] += s0 * wa.z; a0[3] += s0 * wa.w;
      a0[4] += s0 * wb.x; a0[5] += s0 * wb.y; a0[6] += s0 * wb.z; a0[7] += s0 * wb.w;
      a1[0] += s1 * wa.x; a1[1] += s1 * wa.y; a1[2] += s1 * wa.z; a1[3] += s1 * wa.w;
      a1[4] += s1 * wb.x; a1[5] += s1 * wb.y; a1[6] += s1 * wb.z; a1[7] += s1 * wb.w;
    }
  }
  float4 o;
  o.x = a0[0]; o.y = a0[1]; o.z = a0[2]; o.w = a0[3];
  *(float4*)&y[(size_t)r0 * 32 + d0] = o;
  o.x = a0[4]; o.y = a0[5]; o.z = a0[6]; o.w = a0[7];
  *(float4*)&y[(size_t)r0 * 32 + d0 + 4] = o;
  o.x = a1[0]; o.y = a1[1]; o.z = a1[2]; o.w = a1[3];
  *(float4*)&y[(size_t)(r0 + 1) * 32 + d0] = o;
  o.x = a1[4]; o.y = a1[5]; o.z = a1[6]; o.w = a1[7];
  *(float4*)&y[(size_t)(r0 + 1) * 32 + d0 + 4] = o;
}

// ============ shared device helpers for K2 ============
// [ROWS]x32 @ 32x32 from swizzled LDS A into swizzled LDS O; W unswizzled.
template <int ROWS, bool RELU, bool BIAS>
__device__ __forceinline__ void mm_swz(const float* __restrict__ A,
                                       const float* __restrict__ W,
                                       float* __restrict__ O,
                                       const float* __restrict__ bias, int tid) {
  if (tid < ROWS) {
    const int rg = tid >> 2, cg = tid & 3;
    const int n0 = rg * 4, d0 = cg * 8;
    float acc[4][8];
#pragma unroll
    for (int r = 0; r < 4; ++r)
#pragma unroll
      for (int c = 0; c < 8; ++c) acc[r][c] = 0.f;
#pragma unroll
    for (int kc = 0; kc < 8; ++kc) {
      float4 av[4];
#pragma unroll
      for (int r = 0; r < 4; ++r) av[r] = *(const float4*)&A[swz(n0 + r, kc)];
#pragma unroll
      for (int j = 0; j < 4; ++j) {
        const int k = kc * 4 + j;
        const float4 wa = *(const float4*)&W[k * 32 + d0];
        const float4 wb = *(const float4*)&W[k * 32 + d0 + 4];
#pragma unroll
        for (int r = 0; r < 4; ++r) {
          const float xs = (j == 0) ? av[r].x : (j == 1) ? av[r].y
                                  : (j == 2) ? av[r].z : av[r].w;
          acc[r][0] += xs * wa.x; acc[r][1] += xs * wa.y;
          acc[r][2] += xs * wa.z; acc[r][3] += xs * wa.w;
          acc[r][4] += xs * wb.x; acc[r][5] += xs * wb.y;
          acc[r][6] += xs * wb.z; acc[r][7] += xs * wb.w;
        }
      }
    }
#pragma unroll
    for (int r = 0; r < 4; ++r) {
      float v[8];
#pragma unroll
      for (int c = 0; c < 8; ++c) {
        float t = acc[r][c];
        if (BIAS) t += bias[d0 + c];
        if (RELU) t = fmaxf(t, 0.f);
        v[c] = t;
      }
      float4 o0, o1;
      o0.x = v[0]; o0.y = v[1]; o0.z = v[2]; o0.w = v[3];
      o1.x = v[4]; o1.y = v[5]; o1.z = v[6]; o1.w = v[7];
      *(float4*)&O[swz(n0 + r, cg * 2)] = o0;
      *(float4*)&O[swz(n0 + r, cg * 2 + 1)] = o1;
    }
  }
}

// exclusive prefix over 256 counters (4-padded) by one full wave; lane = 0..63
__device__ __forceinline__ void scan_counts(const int* __restrict__ cnt,
                                            int* __restrict__ start, int lane) {
  const int b = lane * 4;
  const int c0 = (cnt[b + 0] + 3) & ~3;
  const int c1 = (cnt[b + 1] + 3) & ~3;
  const int c2 = (cnt[b + 2] + 3) & ~3;
  const int c3 = (cnt[b + 3] + 3) & ~3;
  const int t01 = c0 + c1;
  const int t012 = t01 + c2;
  const int tot = t012 + c3;
  int run = tot;
#pragma unroll
  for (int off = 1; off < 64; off <<= 1) {
    const int t = __shfl_up(run, off);
    if (lane >= off) run += t;
  }
  const int e = run - tot;
  start[b + 0] = e;
  start[b + 1] = e + c0;
  start[b + 2] = e + t01;
  start[b + 3] = e + t012;
}

template <int NN>
__device__ __forceinline__ void aggregate(const float* __restrict__ sYv,
                                          float* __restrict__ sAgv,
                                          const int* __restrict__ sSrcv,
                                          const int* __restrict__ sStartv,
                                          const int* __restrict__ sCntv, int tid) {
  const int slot = tid >> 3, part = tid & 7;
#pragma unroll
  for (int p = 0; p < (NN + 63) / 64; ++p) {
    const int n = p * 64 + slot;
    if (n < NN) {
      const int jb = sStartv[n];
      const int je = jb + sCntv[n];
      float4 a0 = {0, 0, 0, 0}, a1 = {0, 0, 0, 0}, a2 = {0, 0, 0, 0}, a3 = {0, 0, 0, 0};
      int j = jb;
      for (; j + 4 <= je; j += 4) {
        const int4 ss = *(const int4*)&sSrcv[j];
        const float4 v0 = *(const float4*)&sYv[swz(ss.x, part)];
        const float4 v1 = *(const float4*)&sYv[swz(ss.y, part)];
        const float4 v2 = *(const float4*)&sYv[swz(ss.z, part)];
        const float4 v3 = *(const float4*)&sYv[swz(ss.w, part)];
        a0.x += v0.x; a0.y += v0.y; a0.z += v0.z; a0.w += v0.w;
        a1.x += v1.x; a1.y += v1.y; a1.z += v1.z; a1.w += v1.w;
        a2.x += v2.x; a2.y += v2.y; a2.z += v2.z; a2.w += v2.w;
        a3.x += v3.x; a3.y += v3.y; a3.z += v3.z; a3.w += v3.w;
      }
      for (; j < je; ++j) {
        const float4 v = *(const float4*)&sYv[swz(sSrcv[j], part)];
        a0.x += v.x; a0.y += v.y; a0.z += v.z; a0.w += v.w;
      }
      float4 o;
      o.x = (a0.x + a1.x) + (a2.x + a3.x);
      o.y = (a0.y + a1.y) + (a2.y + a3.y);
      o.z = (a0.z + a1.z) + (a2.z + a3.z);
      o.w = (a0.w + a1.w) + (a2.w + a3.w);
      *(float4*)&sAgv[swz(n, part)] = o;
    }
  }
}

// ============ K2: everything after the projection, one block per graph ======
__global__ __launch_bounds__(512, 1) void gin_rest(
    const float* __restrict__ y1g_all, const int* __restrict__ ei,
    const float* __restrict__ b1a, const float* __restrict__ w1b,
    const float* __restrict__ b1b, const float* __restrict__ w2a,
    const float* __restrict__ b2a, const float* __restrict__ w2b,
    const float* __restrict__ b2b, const float* __restrict__ pw1,
    const float* __restrict__ pw2,
    const float* __restrict__ fc1w, const float* __restrict__ fc1b,
    const float* __restrict__ fc2w, const float* __restrict__ fc2b,
    const float* __restrict__ fc3w, const float* __restrict__ fc3b,
    const float* __restrict__ bn1g, const float* __restrict__ bn1b,
    const float* __restrict__ bn1m, const float* __restrict__ bn1v,
    const float* __restrict__ bn2g, const float* __restrict__ bn2b,
    const float* __restrict__ bn2m, const float* __restrict__ bn2v,
    float* __restrict__ out) {
  __shared__ __align__(16) float sY[6400];    // y1 (swz), later y2
  __shared__ __align__(16) float sAg[6400];   // aggr/t (swz)
  __shared__ __align__(16) float sH[6400];    // conv outputs (swz)
  __shared__ __align__(16) float sHp[3200];   // pooled h (swz)
  __shared__ __align__(16) float sW[SW_SIZE];
  __shared__ __align__(16) int sSrc[7040];    // 4-aligned CSR src lists
  __shared__ unsigned short sEdge[6400];      // packed (src<<8)|dst
  __shared__ int sCnt[256];
  __shared__ int sStart[256];
  __shared__ int sOfs[256];
  __shared__ float sScore[256];
  __shared__ int sNewid[256];
  __shared__ float sZ[64];
  __shared__ float sZ1[128];
  __shared__ float sZ2[256];
  __shared__ float sLg[2];

  const int tid = threadIdx.x;
  const int g = blockIdx.x;

  // ---- P0: zero counters, stage y1 (swizzled) + weights ----
  if (tid < 256) { sCnt[tid] = 0; sOfs[tid] = 0; }
  {
    const float* yg = y1g_all + (size_t)g * (NNODE * DIM);
    for (int i = tid; i < 1600; i += 512) {
      const float4 v = *(const float4*)&yg[i * 4];
      *(float4*)&sY[swz(i >> 3, i & 7)] = v;
    }
  }
  for (int i = tid; i < 1024; i += 512) {
    sW[W1B_OFF + i] = w1b[i];
    sW[W2A_OFF + i] = w2a[i];
    sW[W2B_OFF + i] = w2b[i];
  }
  if (tid < 32) {
    sW[B1A_OFF + tid] = b1a[tid];
    sW[B1B_OFF + tid] = b1b[tid];
    sW[B2A_OFF + tid] = b2a[tid];
    sW[B2B_OFF + tid] = b2b[tid];
    sW[PW1_OFF + tid] = pw1[tid];
    sW[PW2_OFF + tid] = pw2[tid];
  }
  __syncthreads();

  // ---- P1: norms; load edges, pack, count in-degree ----
  if (tid == 0) {
    float s = 0.f;
    for (int k = 0; k < 32; ++k) s += sW[PW1_OFF + k] * sW[PW1_OFF + k];
    sW[NRM1_OFF] = sqrtf(s);
  } else if (tid == 1) {
    float s = 0.f;
    for (int k = 0; k < 32; ++k) s += sW[PW2_OFF + k] * sW[PW2_OFF + k];
    sW[NRM2_OFF] = sqrtf(s);
  }
  {
    const int eb = g * EPER, nb = g * NNODE;
    for (int i = tid; i < EPER / 4; i += 512) {
      const int4 ss = *(const int4*)&ei[eb + i * 4];
      const int4 dd = *(const int4*)&ei[ETOT + eb + i * 4];
      const int s0 = ss.x - nb, d0 = dd.x - nb;
      const int s1 = ss.y - nb, d1 = dd.y - nb;
      const int s2 = ss.z - nb, d2 = dd.z - nb;
      const int s3 = ss.w - nb, d3 = dd.w - nb;
      sEdge[i * 4 + 0] = (unsigned short)((s0 << 8) | d0);
      sEdge[i * 4 + 1] = (unsigned short)((s1 << 8) | d1);
      sEdge[i * 4 + 2] = (unsigned short)((s2 << 8) | d2);
      sEdge[i * 4 + 3] = (unsigned short)((s3 << 8) | d3);
      atomicAdd(&sCnt[d0], 1);
      atomicAdd(&sCnt[d1], 1);
      atomicAdd(&sCnt[d2], 1);
      atomicAdd(&sCnt[d3], 1);
    }
  }
  __syncthreads();

  // ---- P2: CSR1 starts (single-wave scan) ----
  if (tid < 64) scan_counts(sCnt, sStart, tid);
  __syncthreads();

  // ---- P3: scatter src ids grouped by dst ----
  for (int e = tid; e < EPER; e += 512) {
    const unsigned short p = sEdge[e];
    const int s = p >> 8, d = p & 255;
    sSrc[sStart[d] + atomicAdd(&sOfs[d], 1)] = s;
  }
  __syncthreads();

  // ---- P4: aggr1 ----
  aggregate<NNODE>(sY, sAg, sSrc, sStart, sCnt, tid);
  __syncthreads();

  // ---- P5: t1 = relu(y1 + aggr1 + b1a); re-zero counters for round 2 ----
  if (tid < 256) { sCnt[tid] = 0; sOfs[tid] = 0; }
  for (int i = tid; i < 1600; i += 512) {
    const int n = i >> 3, ch = i & 7;
    const int p = swz(n, ch);
    const float4 yv = *(const float4*)&sY[p];
    const float4 av = *(const float4*)&sAg[p];
    const float4 bv = *(const float4*)&sW[B1A_OFF + ch * 4];
    float4 t;
    t.x = fmaxf(yv.x + av.x + bv.x, 0.f);
    t.y = fmaxf(yv.y + av.y + bv.y, 0.f);
    t.z = fmaxf(yv.z + av.z + bv.z, 0.f);
    t.w = fmaxf(yv.w + av.w + bv.w, 0.f);
    *(float4*)&sAg[p] = t;
  }
  __syncthreads();

  // ---- P6: h = relu(t1 @ w1b + b1b) ----
  mm_swz<200, true, true>(sAg, &sW[W1B_OFF], sH, &sW[B1B_OFF], tid);
  __syncthreads();

  // ---- P7: pool1 scores ----
  if (tid < NNODE) {
    float dot = 0.f;
#pragma unroll
    for (int kc = 0; kc < 8; ++kc) {
      const float4 v = *(const float4*)&sH[swz(tid, kc)];
      const float4 w = *(const float4*)&sW[PW1_OFF + kc * 4];
      dot += v.x * w.x + v.y * w.y + v.z * w.z + v.w * w.w;
    }
    sScore[tid] = tanhf(dot / sW[NRM1_OFF]);
  }
  __syncthreads();

  // ---- P8: stable descending rank (== lax.top_k order), attn1, newid ----
  if (tid < NNODE) {
    const float s = sScore[tid];
    int r = 0;
    for (int m = 0; m < NNODE; ++m) {
      const float sm = sScore[m];
      r += (sm > s) || (sm == s && m < tid);
    }
    sNewid[tid] = (r < KP1) ? r : -1;
    if (r < KP1) out[2 * NGRAPH + g * KP1 + r] = 1.f / (1.f + expf(-s));
  }
  __syncthreads();

  // ---- P9: hp1 = h[perm]*score; count2 ----
  if (tid < NNODE) {
    const int r = sNewid[tid];
    if (r >= 0) {
      const float sc = sScore[tid];
#pragma unroll
      for (int kc = 0; kc < 8; ++kc) {
        float4 v = *(const float4*)&sH[swz(tid, kc)];
        v.x *= sc; v.y *= sc; v.z *= sc; v.w *= sc;
        *(float4*)&sHp[swz(r, kc)] = v;
      }
    }
  }
  for (int e = tid; e < EPER; e += 512) {
    const unsigned short p = sEdge[e];
    const int s1 = sNewid[p >> 8], d1 = sNewid[p & 255];
    if (s1 >= 0 && d1 >= 0) atomicAdd(&sCnt[d1], 1);
  }
  __syncthreads();

  // ---- P10: x1 readout (wave0 lanes 0..31); CSR2 scan (wave1) ----
  if (tid < 32) {
    const int ch = tid >> 2, w = tid & 3;
    float m0 = -INFINITY, m1 = -INFINITY, s0 = 0.f, s1 = 0.f;
    for (int r = 0; r < KP1; r += 2) {
      const float v0 = sHp[swz(r, ch) + w];
      const float v1 = sHp[swz(r + 1, ch) + w];
      m0 = fmaxf(m0, v0); m1 = fmaxf(m1, v1);
      s0 += v0; s1 += v1;
    }
    sZ[tid] = fmaxf(m0, m1);
    sZ[32 + tid] = (s0 + s1) / (float)KP1;
  } else if (tid >= 64 && tid < 128) {
    scan_counts(sCnt, sStart, tid - 64);
  }
  __syncthreads();

  // ---- P11: y2 = hp1 @ w2a (tid<100) || scatter2 (tid>=128) ----
  mm_swz<KP1, false, false>(sHp, &sW[W2A_OFF], sY, nullptr, tid);
  if (tid >= 128) {
    for (int e = tid - 128; e < EPER; e += 384) {
      const unsigned short p = sEdge[e];
      const int s1 = sNewid[p >> 8], d1 = sNewid[p & 255];
      if (s1 >= 0 && d1 >= 0) sSrc[sStart[d1] + atomicAdd(&sOfs[d1], 1)] = s1;
    }
  }
  __syncthreads();

  // ---- P12: aggr2 ----
  aggregate<KP1>(sY, sAg, sSrc, sStart, sCnt, tid);
  __syncthreads();

  // ---- P13: t2 = relu(y2 + aggr2 + b2a) ----
  for (int i = tid; i < 800; i += 512) {
    const int n = i >> 3, ch = i & 7;
    const int p = swz(n, ch);
    const float4 yv = *(const float4*)&sY[p];
    const float4 av = *(const float4*)&sAg[p];
    const float4 bv = *(const float4*)&sW[B2A_OFF + ch * 4];
    float4 t;
    t.x = fmaxf(yv.x + av.x + bv.x, 0.f);
    t.y = fmaxf(yv.y + av.y + bv.y, 0.f);
    t.z = fmaxf(yv.z + av.z + bv.z, 0.f);
    t.w = fmaxf(yv.w + av.w + bv.w, 0.f);
    *(float4*)&sAg[p] = t;
  }
  __syncthreads();

  // ---- P14: hc2 = relu(t2 @ w2b + b2b) ----
  mm_swz<KP1, true, true>(sAg, &sW[W2B_OFF], sH, &sW[B2B_OFF], tid);
  __syncthreads();

  // ---- P15: pool2 scores ----
  if (tid < KP1) {
    float dot = 0.f;
#pragma unroll
    for (int kc = 0; kc < 8; ++kc) {
      const float4 v = *(const float4*)&sH[swz(tid, kc)];
      const float4 w = *(const float4*)&sW[PW2_OFF + kc * 4];
      dot += v.x * w.x + v.y * w.y + v.z * w.z + v.w * w.w;
    }
    sScore[tid] = tanhf(dot / sW[NRM2_OFF]);
  }
  __syncthreads();

  // ---- P16: rank2, attn2 ----
  if (tid < KP1) {
    const float s = sScore[tid];
    int r = 0;
    for (int m = 0; m < KP1; ++m) {
      const float sm = sScore[m];
      r += (sm > s) || (sm == s && m < tid);
    }
    sNewid[tid] = (r < KP2) ? r : -1;
    if (r < KP2)
      out[2 * NGRAPH + NGRAPH * KP1 + g * KP2 + r] = 1.f / (1.f + expf(-s));
  }
  __syncthreads();

  // ---- P17: hp2 ----
  if (tid < KP1) {
    const int r = sNewid[tid];
    if (r >= 0) {
      const float sc = sScore[tid];
#pragma unroll
      for (int kc = 0; kc < 8; ++kc) {
        float4 v = *(const float4*)&sH[swz(tid, kc)];
        v.x *= sc; v.y *= sc; v.z *= sc; v.w *= sc;
        *(float4*)&sHp[swz(r, kc)] = v;
      }
    }
  }
  __syncthreads();

  // ---- P18: x2 readout, z = x1 + x2 ----
  if (tid < 32) {
    const int ch = tid >> 2, w = tid & 3;
    float m0 = -INFINITY, m1 = -INFINITY, s0 = 0.f, s1 = 0.f;
    for (int r = 0; r < KP2; r += 2) {
      const float v0 = sHp[swz(r, ch) + w];
      const float v1 = sHp[swz(r + 1, ch) + w];
      m0 = fmaxf(m0, v0); m1 = fmaxf(m1, v1);
      s0 += v0; s1 += v1;
    }
    sZ[tid] += fmaxf(m0, m1);
    sZ[32 + tid] += (s0 + s1) / (float)KP2;
  }
  __syncthreads();

  // ---- P19: fc1 + bn1 ----
  if (tid < 128) {
    float a = fc1b[tid];
    for (int k = 0; k < 64; ++k) a += sZ[k] * fc1w[k * 128 + tid];
    a = fmaxf(a, 0.f);
    a = (a - bn1m[tid]) * rsqrtf(bn1v[tid] + 1e-5f) * bn1g[tid] + bn1b[tid];
    sZ1[tid] = a;
  }
  __syncthreads();

  // ---- P20: fc2 + bn2 ----
  if (tid < 256) {
    float a = fc2b[tid];
    for (int k = 0; k < 128; ++k) a += sZ1[k] * fc2w[k * 256 + tid];
    a = fmaxf(a, 0.f);
    a = (a - bn2m[tid]) * rsqrtf(bn2v[tid] + 1e-5f) * bn2g[tid] + bn2b[tid];
    sZ2[tid] = a;
  }
  __syncthreads();

  // ---- P21: fc3 (two waves, shuffle-reduce) ----
  if (tid < 128) {
    const int o = tid >> 6, lane = tid & 63;
    float a = 0.f;
    for (int k = lane; k < 256; k += 64) a += sZ2[k] * fc3w[k * 2 + o];
#pragma unroll
    for (int off = 32; off; off >>= 1) a += __shfl_down(a, off);
    if (lane == 0) sLg[o] = a + fc3b[o];
  }
  __syncthreads();

  // ---- P22: log-softmax ----
  if (tid == 0) {
    const float l0 = sLg[0], l1 = sLg[1];
    const float m = fmaxf(l0, l1);
    const float lse = m + logf(expf(l0 - m) + expf(l1 - m));
    out[g * 2 + 0] = l0 - lse;
    out[g * 2 + 1] = l1 - lse;
  }
}

extern "C" void kernel_launch(void* const* d_in, const int* in_sizes, int n_in,
                              void* d_out, int out_size, void* d_ws,
                              size_t ws_size, hipStream_t stream) {
  (void)in_sizes; (void)n_in; (void)out_size; (void)ws_size;
  float* y1 = (float*)d_ws;  // 128*200*32 f32 = 3.2 MB
  proj_k<<<256, 256, 0, stream>>>((const float*)d_in[0],
                                  (const float*)d_in[3], y1);
  gin_rest<<<NGRAPH, 512, 0, stream>>>(
      y1, (const int*)d_in[1],
      (const float*)d_in[4],   // b1a
      (const float*)d_in[5], (const float*)d_in[6],    // w1b, b1b
      (const float*)d_in[7], (const float*)d_in[8],    // w2a, b2a
      (const float*)d_in[9], (const float*)d_in[10],   // w2b, b2b
      (const float*)d_in[11], (const float*)d_in[12],  // pw1, pw2
      (const float*)d_in[13], (const float*)d_in[14],
      (const float*)d_in[15], (const float*)d_in[16],
      (const float*)d_in[17], (const float*)d_in[18],
      (const float*)d_in[19], (const float*)d_in[20],
      (const float*)d_in[21], (const float*)d_in[22],
      (const float*)d_in[23], (const float*)d_in[24],
      (const float*)d_in[25], (const float*)d_in[26],
      (float*)d_out);
}

// Round 3
// 52.211 us; speedup vs baseline: 1.7682x; 1.2115x over previous
//
#include <hip/hip_runtime.h>
#include <math.h>

#define NGRAPH 128
#define NNODE  200
#define FIN    200
#define DIM    32
#define EPER   6400
#define ETOT   819200
#define KP1    100
#define KP2    50

// sW layout offsets (floats)
#define W1B_OFF  0
#define W2A_OFF  1024
#define W2B_OFF  2048
#define B1A_OFF  3072
#define B1B_OFF  3104
#define B2A_OFF  3136
#define B2B_OFF  3168
#define PW1_OFF  3200
#define PW2_OFF  3232
#define NRM1_OFF 3264
#define NRM2_OFF 3265
#define SW_SIZE  3280

// XOR chunk swizzle for [row][32]-float LDS tiles.
__device__ __forceinline__ int swz(int row, int chunk) {
  return (row << 5) + (((chunk ^ ((row >> 2) & 7))) << 2);
}

// ============ K1: y = x @ w1a (dense 25600x200 @ 200x32) ====
// 512 blocks x 50 rows -> 2 blocks/CU for latency overlap.
__global__ __launch_bounds__(256, 2) void proj_k(const float* __restrict__ x,
                                                 const float* __restrict__ w1a,
                                                 float* __restrict__ y) {
  __shared__ __align__(16) float sw[FIN * DIM];  // 25.6 KB
  const int tid = threadIdx.x;
  for (int i = tid; i < FIN * DIM; i += 256) sw[i] = w1a[i];
  __syncthreads();
  if (tid >= 200) return;
  const int rg = tid >> 2, cg = tid & 3;
  const int d0 = cg * 8;
  const int r0 = blockIdx.x * 50 + rg;  // 512 blocks x 50 rows = 25600
  const float* x0 = x + (size_t)r0 * FIN;
  float a0[8] = {0, 0, 0, 0, 0, 0, 0, 0};
  for (int k = 0; k < FIN; k += 4) {
    const float4 xa = *(const float4*)&x0[k];
#pragma unroll
    for (int j = 0; j < 4; ++j) {
      const float4 wa = *(const float4*)&sw[(k + j) * DIM + d0];
      const float4 wb = *(const float4*)&sw[(k + j) * DIM + d0 + 4];
      const float s0 = (j == 0) ? xa.x : (j == 1) ? xa.y : (j == 2) ? xa.z : xa.w;
      a0[0] += s0 * wa.x; a0[1] += s0 * wa.y; a0[2] += s0 * wa.z; a0[3] += s0 * wa.w;
      a0[4] += s0 * wb.x; a0[5] += s0 * wb.y; a0[6] += s0 * wb.z; a0[7] += s0 * wb.w;
    }
  }
  float4 o;
  o.x = a0[0]; o.y = a0[1]; o.z = a0[2]; o.w = a0[3];
  *(float4*)&y[(size_t)r0 * 32 + d0] = o;
  o.x = a0[4]; o.y = a0[5]; o.z = a0[6]; o.w = a0[7];
  *(float4*)&y[(size_t)r0 * 32 + d0 + 4] = o;
}

// ============ helpers for K2 ============
// [ROWS]x32 @ 32x32, 2 rows/thread (tid < ROWS*2). If FUSE, the A operand is
// relu(A[p] + A2[p] + fb[chunk]) computed on the fly (fuses the GIN add+relu).
template <int ROWS, bool RELU, bool BIAS, bool FUSE>
__device__ __forceinline__ void mm2r(const float* __restrict__ A,
                                     const float* __restrict__ A2,
                                     const float* __restrict__ fb,
                                     const float* __restrict__ W,
                                     float* __restrict__ O,
                                     const float* __restrict__ bias, int tid) {
  if (tid < ROWS * 2) {
    const int rg = tid >> 2, cg = tid & 3;
    const int r0 = rg * 2, d0 = cg * 8;
    float acc[2][8];
#pragma unroll
    for (int r = 0; r < 2; ++r)
#pragma unroll
      for (int c = 0; c < 8; ++c) acc[r][c] = 0.f;
#pragma unroll
    for (int kc = 0; kc < 8; ++kc) {
      float4 av[2];
#pragma unroll
      for (int r = 0; r < 2; ++r) {
        const int p = swz(r0 + r, kc);
        float4 v = *(const float4*)&A[p];
        if (FUSE) {
          const float4 u = *(const float4*)&A2[p];
          const float4 b = *(const float4*)&fb[kc * 4];
          v.x = fmaxf(v.x + u.x + b.x, 0.f);
          v.y = fmaxf(v.y + u.y + b.y, 0.f);
          v.z = fmaxf(v.z + u.z + b.z, 0.f);
          v.w = fmaxf(v.w + u.w + b.w, 0.f);
        }
        av[r] = v;
      }
#pragma unroll
      for (int j = 0; j < 4; ++j) {
        const int k = kc * 4 + j;
        const float4 wa = *(const float4*)&W[k * 32 + d0];
        const float4 wb = *(const float4*)&W[k * 32 + d0 + 4];
#pragma unroll
        for (int r = 0; r < 2; ++r) {
          const float xs = (j == 0) ? av[r].x : (j == 1) ? av[r].y
                                  : (j == 2) ? av[r].z : av[r].w;
          acc[r][0] += xs * wa.x; acc[r][1] += xs * wa.y;
          acc[r][2] += xs * wa.z; acc[r][3] += xs * wa.w;
          acc[r][4] += xs * wb.x; acc[r][5] += xs * wb.y;
          acc[r][6] += xs * wb.z; acc[r][7] += xs * wb.w;
        }
      }
    }
#pragma unroll
    for (int r = 0; r < 2; ++r) {
      float v[8];
#pragma unroll
      for (int c = 0; c < 8; ++c) {
        float t = acc[r][c];
        if (BIAS) t += bias[d0 + c];
        if (RELU) t = fmaxf(t, 0.f);
        v[c] = t;
      }
      float4 o0, o1;
      o0.x = v[0]; o0.y = v[1]; o0.z = v[2]; o0.w = v[3];
      o1.x = v[4]; o1.y = v[5]; o1.z = v[6]; o1.w = v[7];
      *(float4*)&O[swz(r0 + r, cg * 2)] = o0;
      *(float4*)&O[swz(r0 + r, cg * 2 + 1)] = o1;
    }
  }
}

// exclusive prefix over 256 counters (4-padded) by one full wave; lane 0..63
__device__ __forceinline__ void scan_counts(const int* __restrict__ cnt,
                                            int* __restrict__ start, int lane) {
  const int b = lane * 4;
  const int c0 = (cnt[b + 0] + 3) & ~3;
  const int c1 = (cnt[b + 1] + 3) & ~3;
  const int c2 = (cnt[b + 2] + 3) & ~3;
  const int c3 = (cnt[b + 3] + 3) & ~3;
  const int t01 = c0 + c1;
  const int t012 = t01 + c2;
  const int tot = t012 + c3;
  int run = tot;
#pragma unroll
  for (int off = 1; off < 64; off <<= 1) {
    const int t = __shfl_up(run, off);
    if (lane >= off) run += t;
  }
  const int e = run - tot;
  start[b + 0] = e;
  start[b + 1] = e + c0;
  start[b + 2] = e + t01;
  start[b + 3] = e + t012;
}

// 128 node-slots x 8 float4-parts (1024 threads)
template <int NN>
__device__ __forceinline__ void aggregate(const float* __restrict__ sYv,
                                          float* __restrict__ sAgv,
                                          const int* __restrict__ sSrcv,
                                          const int* __restrict__ sStartv,
                                          const int* __restrict__ sCntv, int tid) {
  const int slot = tid >> 3, part = tid & 7;
#pragma unroll
  for (int p = 0; p < (NN + 127) / 128; ++p) {
    const int n = p * 128 + slot;
    if (n < NN) {
      const int jb = sStartv[n];
      const int je = jb + sCntv[n];
      float4 a0 = {0, 0, 0, 0}, a1 = {0, 0, 0, 0}, a2 = {0, 0, 0, 0}, a3 = {0, 0, 0, 0};
      int j = jb;
      for (; j + 4 <= je; j += 4) {
        const int4 ss = *(const int4*)&sSrcv[j];
        const float4 v0 = *(const float4*)&sYv[swz(ss.x, part)];
        const float4 v1 = *(const float4*)&sYv[swz(ss.y, part)];
        const float4 v2 = *(const float4*)&sYv[swz(ss.z, part)];
        const float4 v3 = *(const float4*)&sYv[swz(ss.w, part)];
        a0.x += v0.x; a0.y += v0.y; a0.z += v0.z; a0.w += v0.w;
        a1.x += v1.x; a1.y += v1.y; a1.z += v1.z; a1.w += v1.w;
        a2.x += v2.x; a2.y += v2.y; a2.z += v2.z; a2.w += v2.w;
        a3.x += v3.x; a3.y += v3.y; a3.z += v3.z; a3.w += v3.w;
      }
      for (; j < je; ++j) {
        const float4 v = *(const float4*)&sYv[swz(sSrcv[j], part)];
        a0.x += v.x; a0.y += v.y; a0.z += v.z; a0.w += v.w;
      }
      float4 o;
      o.x = (a0.x + a1.x) + (a2.x + a3.x);
      o.y = (a0.y + a1.y) + (a2.y + a3.y);
      o.z = (a0.z + a1.z) + (a2.z + a3.z);
      o.w = (a0.w + a1.w) + (a2.w + a3.w);
      *(float4*)&sAgv[swz(n, part)] = o;
    }
  }
}

// ============ K2: everything after the projection, one block per graph ======
__global__ __launch_bounds__(1024, 1) void gin_rest(
    const float* __restrict__ y1g_all, const int* __restrict__ ei,
    const float* __restrict__ b1a, const float* __restrict__ w1b,
    const float* __restrict__ b1b, const float* __restrict__ w2a,
    const float* __restrict__ b2a, const float* __restrict__ w2b,
    const float* __restrict__ b2b, const float* __restrict__ pw1,
    const float* __restrict__ pw2,
    const float* __restrict__ fc1w, const float* __restrict__ fc1b,
    const float* __restrict__ fc2w, const float* __restrict__ fc2b,
    const float* __restrict__ fc3w, const float* __restrict__ fc3b,
    const float* __restrict__ bn1g, const float* __restrict__ bn1b,
    const float* __restrict__ bn1m, const float* __restrict__ bn1v,
    const float* __restrict__ bn2g, const float* __restrict__ bn2b,
    const float* __restrict__ bn2m, const float* __restrict__ bn2v,
    float* __restrict__ out) {
  __shared__ __align__(16) float sY[6400];    // y1 (swz), later y2
  __shared__ __align__(16) float sAg[6400];   // aggr (swz)
  __shared__ __align__(16) float sH[6400];    // conv outputs (swz)
  __shared__ __align__(16) float sHp[3200];   // pooled h (swz)
  __shared__ __align__(16) float sW[SW_SIZE];
  __shared__ __align__(16) int sSrc[7040];    // 4-aligned CSR src lists
  __shared__ unsigned short sEdge[6400];      // packed (src<<8)|dst
  __shared__ int sCnt[256], sStart[256], sOfs[256];
  __shared__ int sCnt2[256], sStart2[256], sOfs2[256];
  __shared__ float sScore[256];
  __shared__ int sNewid[256];
  __shared__ float sZ[64];
  __shared__ float sZ1[128];
  __shared__ float sZ2[256];
  __shared__ float sLg[2];

  const int tid = threadIdx.x;
  const int g = blockIdx.x;

  // ---- A: [tid<512] stage y1+weights+zero counters || [tid>=512] pack edges
  if (tid < 512) {
    if (tid < 256) { sCnt[tid] = 0; sOfs[tid] = 0; }
    const float* yg = y1g_all + (size_t)g * (NNODE * DIM);
    for (int i = tid; i < 1600; i += 512) {
      const float4 v = *(const float4*)&yg[i * 4];
      *(float4*)&sY[swz(i >> 3, i & 7)] = v;
    }
    for (int i = tid; i < 1024; i += 512) {
      sW[W1B_OFF + i] = w1b[i];
      sW[W2A_OFF + i] = w2a[i];
      sW[W2B_OFF + i] = w2b[i];
    }
    if (tid < 32) {
      sW[B1A_OFF + tid] = b1a[tid];
      sW[B1B_OFF + tid] = b1b[tid];
      sW[B2A_OFF + tid] = b2a[tid];
      sW[B2B_OFF + tid] = b2b[tid];
      sW[PW1_OFF + tid] = pw1[tid];
      sW[PW2_OFF + tid] = pw2[tid];
    }
  } else {
    const int eb = g * EPER, nb = g * NNODE;
    for (int i = tid - 512; i < EPER / 4; i += 512) {
      const int4 ss = *(const int4*)&ei[eb + i * 4];
      const int4 dd = *(const int4*)&ei[ETOT + eb + i * 4];
      sEdge[i * 4 + 0] = (unsigned short)(((ss.x - nb) << 8) | (dd.x - nb));
      sEdge[i * 4 + 1] = (unsigned short)(((ss.y - nb) << 8) | (dd.y - nb));
      sEdge[i * 4 + 2] = (unsigned short)(((ss.z - nb) << 8) | (dd.z - nb));
      sEdge[i * 4 + 3] = (unsigned short)(((ss.w - nb) << 8) | (dd.w - nb));
    }
  }
  __syncthreads();

  // ---- B: count in-degree (8 edges/thread) + pw norms ----
  if (tid == 0) {
    float s = 0.f;
    for (int k = 0; k < 32; ++k) s += sW[PW1_OFF + k] * sW[PW1_OFF + k];
    sW[NRM1_OFF] = sqrtf(s);
  } else if (tid == 1) {
    float s = 0.f;
    for (int k = 0; k < 32; ++k) s += sW[PW2_OFF + k] * sW[PW2_OFF + k];
    sW[NRM2_OFF] = sqrtf(s);
  }
  if (tid < 800) {
    const uint4 u = *(const uint4*)&sEdge[tid * 8];
    atomicAdd(&sCnt[u.x & 255], 1);
    atomicAdd(&sCnt[(u.x >> 16) & 255], 1);
    atomicAdd(&sCnt[u.y & 255], 1);
    atomicAdd(&sCnt[(u.y >> 16) & 255], 1);
    atomicAdd(&sCnt[u.z & 255], 1);
    atomicAdd(&sCnt[(u.z >> 16) & 255], 1);
    atomicAdd(&sCnt[u.w & 255], 1);
    atomicAdd(&sCnt[(u.w >> 16) & 255], 1);
  }
  __syncthreads();

  // ---- C: CSR1 starts ----
  if (tid < 64) scan_counts(sCnt, sStart, tid);
  __syncthreads();

  // ---- D: scatter src ids grouped by dst ----
  for (int e = tid; e < EPER; e += 1024) {
    const unsigned short p = sEdge[e];
    sSrc[sStart[p & 255] + atomicAdd(&sOfs[p & 255], 1)] = p >> 8;
  }
  __syncthreads();

  // ---- E: aggr1 ----
  aggregate<NNODE>(sY, sAg, sSrc, sStart, sCnt, tid);
  __syncthreads();

  // ---- F: h = relu(relu(y1+aggr1+b1a) @ w1b + b1b)  (t1 fused into A-read)
  //      idle threads zero round-2 counters
  mm2r<200, true, true, true>(sY, sAg, &sW[B1A_OFF], &sW[W1B_OFF], sH,
                              &sW[B1B_OFF], tid);
  if (tid >= 512) {
    const int i = tid - 512;
    if (i < 256) sCnt2[i] = 0;
    else if (i < 512) sOfs2[i - 256] = 0;
  }
  __syncthreads();

  // ---- G: pool1 scores ----
  if (tid < NNODE) {
    float dot = 0.f;
#pragma unroll
    for (int kc = 0; kc < 8; ++kc) {
      const float4 v = *(const float4*)&sH[swz(tid, kc)];
      const float4 w = *(const float4*)&sW[PW1_OFF + kc * 4];
      dot += v.x * w.x + v.y * w.y + v.z * w.z + v.w * w.w;
    }
    sScore[tid] = tanhf(dot / sW[NRM1_OFF]);
  }
  __syncthreads();

  // ---- H: stable descending rank (4-way split + shfl combine), attn1 ----
  if (tid < NNODE * 4) {
    const int n = tid >> 2, q = tid & 3;
    const float s = sScore[n];
    int r = 0;
    for (int m = q * 50; m < q * 50 + 50; ++m) {
      const float sm = sScore[m];
      r += (sm > s) || (sm == s && m < n);
    }
    r += __shfl_xor(r, 1);
    r += __shfl_xor(r, 2);
    if (q == 0) {
      sNewid[n] = (r < KP1) ? r : -1;
      if (r < KP1) out[2 * NGRAPH + g * KP1 + r] = 1.f / (1.f + expf(-s));
    }
  }
  __syncthreads();

  // ---- I: hp1 = h[perm]*score (tid<400) || count2 (tid>=512) ----
  if (tid < 400) {
    const int n = tid >> 1, kb = (tid & 1) * 4;
    const int r = sNewid[n];
    if (r >= 0) {
      const float sc = sScore[n];
#pragma unroll
      for (int k = 0; k < 4; ++k) {
        float4 v = *(const float4*)&sH[swz(n, kb + k)];
        v.x *= sc; v.y *= sc; v.z *= sc; v.w *= sc;
        *(float4*)&sHp[swz(r, kb + k)] = v;
      }
    }
  } else if (tid >= 512) {
    for (int e = tid - 512; e < EPER; e += 512) {
      const unsigned short p = sEdge[e];
      const int s1 = sNewid[p >> 8], d1 = sNewid[p & 255];
      if (s1 >= 0 && d1 >= 0) atomicAdd(&sCnt2[d1], 1);
    }
  }
  __syncthreads();

  // ---- J: x1 readout (tid<32) || CSR2 scan (wave 1) ----
  if (tid < 32) {
    const int ch = tid >> 2, w = tid & 3;
    float m0 = -INFINITY, m1 = -INFINITY, s0 = 0.f, s1 = 0.f;
    for (int r = 0; r < KP1; r += 2) {
      const float v0 = sHp[swz(r, ch) + w];
      const float v1 = sHp[swz(r + 1, ch) + w];
      m0 = fmaxf(m0, v0); m1 = fmaxf(m1, v1);
      s0 += v0; s1 += v1;
    }
    sZ[tid] = fmaxf(m0, m1);
    sZ[32 + tid] = (s0 + s1) / (float)KP1;
  } else if (tid >= 64 && tid < 128) {
    scan_counts(sCnt2, sStart2, tid - 64);
  }
  __syncthreads();

  // ---- K: y2 = hp1 @ w2a (tid<200) || scatter2 (tid>=256) ----
  mm2r<KP1, false, false, false>(sHp, nullptr, nullptr, &sW[W2A_OFF], sY,
                                 nullptr, tid);
  if (tid >= 256) {
    for (int e = tid - 256; e < EPER; e += 768) {
      const unsigned short p = sEdge[e];
      const int s1 = sNewid[p >> 8], d1 = sNewid[p & 255];
      if (s1 >= 0 && d1 >= 0)
        sSrc[sStart2[d1] + atomicAdd(&sOfs2[d1], 1)] = s1;
    }
  }
  __syncthreads();

  // ---- L: aggr2 ----
  aggregate<KP1>(sY, sAg, sSrc, sStart2, sCnt2, tid);
  __syncthreads();

  // ---- M: hc2 = relu(relu(y2+aggr2+b2a) @ w2b + b2b) ----
  mm2r<KP1, true, true, true>(sY, sAg, &sW[B2A_OFF], &sW[W2B_OFF], sH,
                              &sW[B2B_OFF], tid);
  __syncthreads();

  // ---- N: pool2 scores ----
  if (tid < KP1) {
    float dot = 0.f;
#pragma unroll
    for (int kc = 0; kc < 8; ++kc) {
      const float4 v = *(const float4*)&sH[swz(tid, kc)];
      const float4 w = *(const float4*)&sW[PW2_OFF + kc * 4];
      dot += v.x * w.x + v.y * w.y + v.z * w.z + v.w * w.w;
    }
    sScore[tid] = tanhf(dot / sW[NRM2_OFF]);
  }
  __syncthreads();

  // ---- O: rank2 + attn2 ----
  if (tid < KP1 * 4) {
    const int n = tid >> 2, q = tid & 3;
    const float s = sScore[n];
    int r = 0;
    for (int m = q * 25; m < q * 25 + 25; ++m) {
      const float sm = sScore[m];
      r += (sm > s) || (sm == s && m < n);
    }
    r += __shfl_xor(r, 1);
    r += __shfl_xor(r, 2);
    if (q == 0) {
      sNewid[n] = (r < KP2) ? r : -1;
      if (r < KP2)
        out[2 * NGRAPH + NGRAPH * KP1 + g * KP2 + r] = 1.f / (1.f + expf(-s));
    }
  }
  __syncthreads();

  // ---- P: hp2 ----
  if (tid < 200) {
    const int n = tid >> 1, kb = (tid & 1) * 4;
    const int r = sNewid[n];
    if (r >= 0) {
      const float sc = sScore[n];
#pragma unroll
      for (int k = 0; k < 4; ++k) {
        float4 v = *(const float4*)&sH[swz(n, kb + k)];
        v.x *= sc; v.y *= sc; v.z *= sc; v.w *= sc;
        *(float4*)&sHp[swz(r, kb + k)] = v;
      }
    }
  }
  __syncthreads();

  // ---- Q: x2 readout, z = x1 + x2 ----
  if (tid < 32) {
    const int ch = tid >> 2, w = tid & 3;
    float m0 = -INFINITY, m1 = -INFINITY, s0 = 0.f, s1 = 0.f;
    for (int r = 0; r < KP2; r += 2) {
      const float v0 = sHp[swz(r, ch) + w];
      const float v1 = sHp[swz(r + 1, ch) + w];
      m0 = fmaxf(m0, v0); m1 = fmaxf(m1, v1);
      s0 += v0; s1 += v1;
    }
    sZ[tid] += fmaxf(m0, m1);
    sZ[32 + tid] += (s0 + s1) / (float)KP2;
  }
  __syncthreads();

  // ---- R: fc1 + bn1 ----
  if (tid < 128) {
    float a = fc1b[tid];
    for (int k = 0; k < 64; ++k) a += sZ[k] * fc1w[k * 128 + tid];
    a = fmaxf(a, 0.f);
    a = (a - bn1m[tid]) * rsqrtf(bn1v[tid] + 1e-5f) * bn1g[tid] + bn1b[tid];
    sZ1[tid] = a;
  }
  __syncthreads();

  // ---- S: fc2 + bn2 ----
  if (tid < 256) {
    float a = fc2b[tid];
    for (int k = 0; k < 128; ++k) a += sZ1[k] * fc2w[k * 256 + tid];
    a = fmaxf(a, 0.f);
    a = (a - bn2m[tid]) * rsqrtf(bn2v[tid] + 1e-5f) * bn2g[tid] + bn2b[tid];
    sZ2[tid] = a;
  }
  __syncthreads();

  // ---- T: fc3 (two waves, shuffle-reduce) ----
  if (tid < 128) {
    const int o = tid >> 6, lane = tid & 63;
    float a = 0.f;
    for (int k = lane; k < 256; k += 64) a += sZ2[k] * fc3w[k * 2 + o];
#pragma unroll
    for (int off = 32; off; off >>= 1) a += __shfl_down(a, off);
    if (lane == 0) sLg[o] = a + fc3b[o];
  }
  __syncthreads();

  // ---- U: log-softmax ----
  if (tid == 0) {
    const float l0 = sLg[0], l1 = sLg[1];
    const float m = fmaxf(l0, l1);
    const float lse = m + logf(expf(l0 - m) + expf(l1 - m));
    out[g * 2 + 0] = l0 - lse;
    out[g * 2 + 1] = l1 - lse;
  }
}

extern "C" void kernel_launch(void* const* d_in, const int* in_sizes, int n_in,
                              void* d_out, int out_size, void* d_ws,
                              size_t ws_size, hipStream_t stream) {
  (void)in_sizes; (void)n_in; (void)out_size; (void)ws_size;
  float* y1 = (float*)d_ws;  // 128*200*32 f32 = 3.2 MB
  proj_k<<<512, 256, 0, stream>>>((const float*)d_in[0],
                                  (const float*)d_in[3], y1);
  gin_rest<<<NGRAPH, 1024, 0, stream>>>(
      y1, (const int*)d_in[1],
      (const float*)d_in[4],   // b1a
      (const float*)d_in[5], (const float*)d_in[6],    // w1b, b1b
      (const float*)d_in[7], (const float*)d_in[8],    // w2a, b2a
      (const float*)d_in[9], (const float*)d_in[10],   // w2b, b2b
      (const float*)d_in[11], (const float*)d_in[12],  // pw1, pw2
      (const float*)d_in[13], (const float*)d_in[14],
      (const float*)d_in[15], (const float*)d_in[16],
      (const float*)d_in[17], (const float*)d_in[18],
      (const float*)d_in[19], (const float*)d_in[20],
      (const float*)d_in[21], (const float*)d_in[22],
      (const float*)d_in[23], (const float*)d_in[24],
      (const float*)d_in[25], (const float*)d_in[26],
      (float*)d_out);
}